// Round 1
// baseline (1268.748 us; speedup 1.0000x reference)
//
#include <hip/hip_runtime.h>
#include <math.h>

#define N_NODES 50000
#define N_EDGES 800000
#define C 128
#define OUTC 64

// ---------------------------------------------------------------------------
// CSR build: count degrees into off[dst+1], scan, then fill sorted src list.
// ---------------------------------------------------------------------------

__global__ void k_count(const int* __restrict__ dst, int* __restrict__ off) {
    int e = blockIdx.x * blockDim.x + threadIdx.x;
    if (e < N_EDGES) atomicAdd(&off[dst[e] + 1], 1);
}

// Single-block inclusive scan over off[1..N] (off[0] stays 0). Also emits
// rinv[i] = 1/max(deg_i,1).
__global__ void k_scan(int* __restrict__ off, float* __restrict__ rinv) {
    __shared__ int buf[1024];
    __shared__ int s_carry;
    if (threadIdx.x == 0) s_carry = 0;
    __syncthreads();
    for (int base = 0; base < N_NODES; base += 1024) {
        int i = base + threadIdx.x;
        int deg = (i < N_NODES) ? off[i + 1] : 0;
        buf[threadIdx.x] = deg;
        __syncthreads();
        for (int s = 1; s < 1024; s <<= 1) {
            int add = (threadIdx.x >= s) ? buf[threadIdx.x - s] : 0;
            __syncthreads();
            buf[threadIdx.x] += add;
            __syncthreads();
        }
        int carry = s_carry;                 // read BEFORE update barrier
        int incl = buf[threadIdx.x] + carry;
        if (i < N_NODES) {
            off[i + 1] = incl;
            rinv[i] = 1.0f / (float)((deg > 1) ? deg : 1);
        }
        __syncthreads();
        if (threadIdx.x == 1023) s_carry = carry + buf[1023];
        __syncthreads();
    }
}

__global__ void k_fill(const int* __restrict__ src, const int* __restrict__ dst,
                       const int* __restrict__ off, int* __restrict__ cur,
                       int* __restrict__ srcs) {
    int e = blockIdx.x * blockDim.x + threadIdx.x;
    if (e < N_EDGES) {
        int d = dst[e];
        int pos = off[d] + atomicAdd(&cur[d], 1);
        srcs[pos] = src[e];
    }
}

// ---------------------------------------------------------------------------
// Aggregation: one wave per node; lane reads float2 of each neighbor row.
// agg[i] = (1/max(deg,1)) * sum_{j in N(i)} h[j]
// ---------------------------------------------------------------------------

__global__ __launch_bounds__(256) void k_aggregate(
    const float2* __restrict__ h, const int* __restrict__ off,
    const int* __restrict__ srcs, const float* __restrict__ rinv,
    float2* __restrict__ agg) {
    int node = blockIdx.x * 4 + (threadIdx.x >> 6);
    if (node >= N_NODES) return;
    int lane = threadIdx.x & 63;
    int b = off[node], e = off[node + 1];
    float sx = 0.f, sy = 0.f;
    for (int j = b; j < e; ++j) {
        int s = srcs[j];
        float2 v = h[s * 64 + lane];
        sx += v.x;
        sy += v.y;
    }
    float r = rinv[node];
    float2 o;
    o.x = sx * r;
    o.y = sy * r;
    agg[node * 64 + lane] = o;
}

// ---------------------------------------------------------------------------
// SAGE update: out = relu(mean@Wl + bl + hin@Wr). Weights staged in LDS
// (128 KiB -> 1 block/CU). Thread = (node_sub, channel); 2 nodes per block
// iteration; next pair's rows prefetched into registers during compute.
// NOTE: `mean` may alias `out` (safe: each node's mean is only read by the
// block that later writes its out, in program order) -> no __restrict__ there.
// ---------------------------------------------------------------------------

__global__ __launch_bounds__(256, 1) void k_sage_mm(
    const float* mean, const float* __restrict__ hin,
    const float* __restrict__ Wl, const float* __restrict__ bl,
    const float* __restrict__ Wr, float* out) {
    __shared__ float sWl[C * C];
    __shared__ float sWr[C * C];
    __shared__ float sb[C];
    __shared__ __align__(16) float rows[2][2][C];

    for (int idx = threadIdx.x; idx < C * C; idx += 256) {
        sWl[idx] = Wl[idx];
        sWr[idx] = Wr[idx];
    }
    if (threadIdx.x < C) sb[threadIdx.x] = bl[threadIdx.x];
    __syncthreads();

    const int nsub = threadIdx.x >> 7;       // 0 or 1
    const int c = threadIdx.x & (C - 1);
    const int NPAIR = N_NODES / 2;           // 50000 is even

    int pair = blockIdx.x;
    float mv = 0.f, hv = 0.f;
    if (pair < NPAIR) {
        int node = pair * 2 + nsub;
        mv = mean[node * C + c];
        hv = hin[node * C + c];
    }
    for (; pair < NPAIR; pair += gridDim.x) {
        int node = pair * 2 + nsub;
        rows[nsub][0][c] = mv;
        rows[nsub][1][c] = hv;
        __syncthreads();
        // prefetch next pair while computing this one
        int pnext = pair + gridDim.x;
        if (pnext < NPAIR) {
            int noden = pnext * 2 + nsub;
            mv = mean[noden * C + c];
            hv = hin[noden * C + c];
        }
        float acc0 = sb[c], acc1 = 0.f;
        const float4* m4 = (const float4*)rows[nsub][0];
        const float4* h4 = (const float4*)rows[nsub][1];
#pragma unroll
        for (int k4 = 0; k4 < C / 4; ++k4) {
            float4 mv4 = m4[k4];
            float4 hv4 = h4[k4];
            int k = k4 * 4;
            acc0 += mv4.x * sWl[(k + 0) * C + c];
            acc1 += hv4.x * sWr[(k + 0) * C + c];
            acc0 += mv4.y * sWl[(k + 1) * C + c];
            acc1 += hv4.y * sWr[(k + 1) * C + c];
            acc0 += mv4.z * sWl[(k + 2) * C + c];
            acc1 += hv4.z * sWr[(k + 2) * C + c];
            acc0 += mv4.w * sWl[(k + 3) * C + c];
            acc1 += hv4.w * sWr[(k + 3) * C + c];
        }
        float v = acc0 + acc1;
        out[node * C + c] = (v > 0.f) ? v : 0.f;
        __syncthreads();
    }
}

// ---------------------------------------------------------------------------
// Final: logits = h@Wlin + blin, then row log_softmax (64 ch = 1 wave).
// ---------------------------------------------------------------------------

__global__ __launch_bounds__(256) void k_out(
    const float* __restrict__ h, const float* __restrict__ Wlin,
    const float* __restrict__ blin, float* __restrict__ out) {
    __shared__ float sW[C * OUTC];
    __shared__ float sb[OUTC];
    __shared__ __align__(16) float rows[4][C];

    for (int idx = threadIdx.x; idx < C * OUTC; idx += 256) sW[idx] = Wlin[idx];
    if (threadIdx.x < OUTC) sb[threadIdx.x] = blin[threadIdx.x];
    __syncthreads();

    int wv = threadIdx.x >> 6;
    int lane = threadIdx.x & 63;
    for (int node = blockIdx.x * 4 + wv; node < N_NODES; node += gridDim.x * 4) {
        rows[wv][lane] = h[node * C + lane];
        rows[wv][64 + lane] = h[node * C + 64 + lane];
        // wave-local LDS producer/consumer: compiler inserts lgkmcnt waits
        float acc = sb[lane];
        const float4* r4 = (const float4*)rows[wv];
#pragma unroll
        for (int k4 = 0; k4 < C / 4; ++k4) {
            float4 rv = r4[k4];
            int k = k4 * 4;
            acc += rv.x * sW[(k + 0) * OUTC + lane];
            acc += rv.y * sW[(k + 1) * OUTC + lane];
            acc += rv.z * sW[(k + 2) * OUTC + lane];
            acc += rv.w * sW[(k + 3) * OUTC + lane];
        }
        float m = acc;
#pragma unroll
        for (int o = 32; o > 0; o >>= 1) m = fmaxf(m, __shfl_xor(m, o, 64));
        float ex = __expf(acc - m);
        float ssum = ex;
#pragma unroll
        for (int o = 32; o > 0; o >>= 1) ssum += __shfl_xor(ssum, o, 64);
        out[node * OUTC + lane] = (acc - m) - __logf(ssum);
    }
}

// ---------------------------------------------------------------------------

extern "C" void kernel_launch(void* const* d_in, const int* in_sizes, int n_in,
                              void* d_out, int out_size, void* d_ws,
                              size_t ws_size, hipStream_t stream) {
    const float* x = (const float*)d_in[0];
    const int* ei = (const int*)d_in[1];           // int32 (jax x64 disabled)
    const int* src = ei;
    const int* dst = ei + N_EDGES;
    const float* Wl0 = (const float*)d_in[2];
    const float* bl0 = (const float*)d_in[3];
    const float* Wr0 = (const float*)d_in[4];
    const float* Wl1 = (const float*)d_in[5];
    const float* bl1 = (const float*)d_in[6];
    const float* Wr1 = (const float*)d_in[7];
    const float* Wl2 = (const float*)d_in[8];
    const float* bl2 = (const float*)d_in[9];
    const float* Wr2 = (const float*)d_in[10];
    const float* Wlin = (const float*)d_in[11];
    const float* blin = (const float*)d_in[12];

    // workspace layout
    int* off = (int*)d_ws;                         // N+1
    int* cur = off + (N_NODES + 1);                // N
    int* srcs = cur + N_NODES;                     // E
    float* rinv = (float*)(srcs + N_EDGES);        // N
    float* bufA = rinv + N_NODES;                  // N*C
    float* bufB = bufA + (size_t)N_NODES * C;      // N*C

    // zero off + cur (contiguous)
    hipMemsetAsync(off, 0, (size_t)(2 * N_NODES + 1) * sizeof(int), stream);

    const int EB = (N_EDGES + 255) / 256;
    k_count<<<EB, 256, 0, stream>>>(dst, off);
    k_scan<<<1, 1024, 0, stream>>>(off, rinv);
    k_fill<<<EB, 256, 0, stream>>>(src, dst, off, cur, srcs);

    const int AGG_GRID = (N_NODES + 3) / 4;

    // layer 0: agg(x)->A ; A = relu(A@Wl0 + b + x@Wr0)  (out aliases mean)
    k_aggregate<<<AGG_GRID, 256, 0, stream>>>((const float2*)x, off, srcs,
                                              rinv, (float2*)bufA);
    k_sage_mm<<<256, 256, 0, stream>>>(bufA, x, Wl0, bl0, Wr0, bufA);

    // layer 1: agg(A)->B ; B = relu(B@Wl1 + b + A@Wr1)
    k_aggregate<<<AGG_GRID, 256, 0, stream>>>((const float2*)bufA, off, srcs,
                                              rinv, (float2*)bufB);
    k_sage_mm<<<256, 256, 0, stream>>>(bufB, bufA, Wl1, bl1, Wr1, bufB);

    // layer 2: agg(B)->A ; A = relu(A@Wl2 + b + B@Wr2)
    k_aggregate<<<AGG_GRID, 256, 0, stream>>>((const float2*)bufB, off, srcs,
                                              rinv, (float2*)bufA);
    k_sage_mm<<<256, 256, 0, stream>>>(bufA, bufB, Wl2, bl2, Wr2, bufA);

    // final projection + log_softmax
    k_out<<<1024, 256, 0, stream>>>(bufA, Wlin, blin, (float*)d_out);
}

// Round 2
// 390.425 us; speedup vs baseline: 3.2497x; 3.2497x over previous
//
#include <hip/hip_runtime.h>
#include <math.h>

#define N_NODES 50000
#define N_EDGES 800000
#define C 128
#define OUTC 64

typedef __attribute__((ext_vector_type(8))) short bfrag;   // 8 bf16 (4 VGPRs)
typedef __attribute__((ext_vector_type(4))) float ffrag;   // 4 fp32 acc

__device__ __forceinline__ ushort f2bf(float f) {
    uint u = __builtin_bit_cast(uint, f);
    uint r = (u + 0x7FFFu + ((u >> 16) & 1u)) >> 16;       // RNE
    return (ushort)r;
}
__device__ __forceinline__ float bflo(uint v) {            // low bf16 of packed pair
    uint u = v << 16; return __builtin_bit_cast(float, u);
}
__device__ __forceinline__ float bfhi(uint v) {            // high bf16
    uint u = v & 0xFFFF0000u; return __builtin_bit_cast(float, u);
}

// ---------------------------------------------------------------------------
// CSR build
// ---------------------------------------------------------------------------

__global__ void k_count(const int* __restrict__ dst, int* __restrict__ off) {
    int e = blockIdx.x * blockDim.x + threadIdx.x;
    if (e < N_EDGES) atomicAdd(&off[dst[e] + 1], 1);
}

__global__ void k_scan(int* __restrict__ off, float* __restrict__ rinv) {
    __shared__ int buf[1024];
    __shared__ int s_carry;
    if (threadIdx.x == 0) s_carry = 0;
    __syncthreads();
    for (int base = 0; base < N_NODES; base += 1024) {
        int i = base + threadIdx.x;
        int deg = (i < N_NODES) ? off[i + 1] : 0;
        buf[threadIdx.x] = deg;
        __syncthreads();
        for (int s = 1; s < 1024; s <<= 1) {
            int add = (threadIdx.x >= s) ? buf[threadIdx.x - s] : 0;
            __syncthreads();
            buf[threadIdx.x] += add;
            __syncthreads();
        }
        int carry = s_carry;
        int incl = buf[threadIdx.x] + carry;
        if (i < N_NODES) {
            off[i + 1] = incl;
            rinv[i] = 1.0f / (float)((deg > 1) ? deg : 1);
        }
        __syncthreads();
        if (threadIdx.x == 1023) s_carry = carry + buf[1023];
        __syncthreads();
    }
}

__global__ void k_fill(const int* __restrict__ src, const int* __restrict__ dst,
                       const int* __restrict__ off, int* __restrict__ cur,
                       int* __restrict__ srcs) {
    int e = blockIdx.x * blockDim.x + threadIdx.x;
    if (e < N_EDGES) {
        int d = dst[e];
        int pos = off[d] + atomicAdd(&cur[d], 1);
        srcs[pos] = src[e];
    }
}

// ---------------------------------------------------------------------------
// casts / weight packing
// ---------------------------------------------------------------------------

__global__ __launch_bounds__(256) void k_cast_x(const float4* __restrict__ x,
                                                uint2* __restrict__ xb) {
    int i = blockIdx.x * 256 + threadIdx.x;            // over N*C/4 float4s
    float4 v = x[i];
    uint2 o;
    o.x = (uint)f2bf(v.x) | ((uint)f2bf(v.y) << 16);
    o.y = (uint)f2bf(v.z) | ((uint)f2bf(v.w) << 16);
    xb[i] = o;
}

// Pack [Wl;Wr] (K=256, N=128) into fragment-linear bf16:
// dst[((nf*8 + ks)*64 + lane)*8 + j] = Wcat[k][n],
//   n = nf*16 + (lane&15), k = ks*32 + (lane>>4)*8 + j
__global__ __launch_bounds__(256) void k_prep_w(const float* __restrict__ Wl,
                                                const float* __restrict__ Wr,
                                                ushort* __restrict__ dst) {
    int idx = blockIdx.x * 256 + threadIdx.x;          // 0..32767
    int j = idx & 7;
    int lane = (idx >> 3) & 63;
    int ks = (idx >> 9) & 7;
    int nf = idx >> 12;
    int n = nf * 16 + (lane & 15);
    int k = ks * 32 + (lane >> 4) * 8 + j;
    float v = (k < C) ? Wl[k * C + n] : Wr[(k - C) * C + n];
    dst[idx] = f2bf(v);
}

// ---------------------------------------------------------------------------
// Aggregation: wave per node, bf16 rows (lane = 2 channels), 4-deep unroll
// with shfl-broadcast neighbor indices for MLP latency hiding.
// ---------------------------------------------------------------------------

__global__ __launch_bounds__(256) void k_aggregate(
    const uint* __restrict__ hb, const int* __restrict__ off,
    const int* __restrict__ srcs, const float* __restrict__ rinv,
    uint* __restrict__ aggb) {
    int node = blockIdx.x * 4 + (threadIdx.x >> 6);
    if (node >= N_NODES) return;
    int lane = threadIdx.x & 63;
    int b = off[node], e = off[node + 1];
    float sx = 0.f, sy = 0.f;
    for (int j0 = b; j0 < e; j0 += 64) {
        int cnt = e - j0;
        if (cnt > 64) cnt = 64;
        int idx = j0 + lane;
        int sv = srcs[(idx < e) ? idx : (e - 1)];
        int k = 0;
        for (; k + 4 <= cnt; k += 4) {
            int s0 = __shfl(sv, k), s1 = __shfl(sv, k + 1);
            int s2 = __shfl(sv, k + 2), s3 = __shfl(sv, k + 3);
            uint v0 = hb[s0 * 64 + lane], v1 = hb[s1 * 64 + lane];
            uint v2 = hb[s2 * 64 + lane], v3 = hb[s3 * 64 + lane];
            sx += bflo(v0) + bflo(v1) + bflo(v2) + bflo(v3);
            sy += bfhi(v0) + bfhi(v1) + bfhi(v2) + bfhi(v3);
        }
        for (; k < cnt; ++k) {
            int s = __shfl(sv, k);
            uint v = hb[s * 64 + lane];
            sx += bflo(v);
            sy += bfhi(v);
        }
    }
    float r = rinv[node];
    aggb[node * 64 + lane] = (uint)f2bf(sx * r) | ((uint)f2bf(sy * r) << 16);
}

// ---------------------------------------------------------------------------
// MFMA GEMM: out = relu([mean||h] @ Wcat + bl), M-tile 64 nodes, N=128, K=256.
// 4 waves: wave = (wm = node-half, wn = ch-half); per wave 2x4 16x16 frags.
// A staged in LDS with XOR chunk swizzle (G4); B read fragment-linear from
// global (L1/L2-hot). `mean` may alias `out` (per-block row ownership).
// ---------------------------------------------------------------------------

__global__ __launch_bounds__(256) void k_mm_mfma(
    const ushort* mean_b, const ushort* __restrict__ h_b,
    const ushort* __restrict__ Wp, const float* __restrict__ bl,
    ushort* out_b) {
    __shared__ __align__(16) ushort A[64 * 256];   // [row][256 kk], 16B chunks XOR-swizzled

    const int t = threadIdx.x;
    const int node0 = blockIdx.x * 64;

    // --- stage A: thread -> row r = t>>2, chunk-group (t&3)*8 .. +8
    {
        int r = t >> 2;
        int node = node0 + r;
        int cg = (t & 3) * 8;
        for (int i = 0; i < 8; ++i) {
            int c = cg + i;                       // chunk = 8 bf16 = 16B
            uint4 v = make_uint4(0u, 0u, 0u, 0u);
            if (node < N_NODES) {
                int kk = c * 8;
                const ushort* sp = (kk < C) ? &mean_b[node * C + kk]
                                            : &h_b[node * C + (kk - C)];
                v = *(const uint4*)sp;
            }
            int cs = c ^ (r & 7);
            *(uint4*)&A[r * 256 + cs * 8] = v;
        }
    }
    __syncthreads();

    const int w = t >> 6, lane = t & 63;
    const int wm = w >> 1, wn = w & 1;
    const int lg = lane >> 4, lr = lane & 15;

    ffrag acc[2][4];
#pragma unroll
    for (int im = 0; im < 2; ++im)
#pragma unroll
        for (int in = 0; in < 4; ++in) acc[im][in] = (ffrag)0.f;

#pragma unroll 2
    for (int ks = 0; ks < 8; ++ks) {
        bfrag a[2];
#pragma unroll
        for (int im = 0; im < 2; ++im) {
            int r = wm * 32 + im * 16 + lr;
            int c = ks * 4 + lg;                  // chunk index (32 per row)
            int cs = c ^ (r & 7);
            a[im] = *(const bfrag*)&A[r * 256 + cs * 8];
        }
        bfrag b[4];
#pragma unroll
        for (int in = 0; in < 4; ++in) {
            int nf = wn * 4 + in;
            b[in] = *(const bfrag*)&Wp[(((nf * 8) + ks) * 64 + lane) * 8];
        }
#pragma unroll
        for (int im = 0; im < 2; ++im)
#pragma unroll
            for (int in = 0; in < 4; ++in)
                acc[im][in] = __builtin_amdgcn_mfma_f32_16x16x32_bf16(
                    a[im], b[in], acc[im][in], 0, 0, 0);
    }

    // --- epilogue: D row = (lane>>4)*4 + reg, col = lane&15
#pragma unroll
    for (int im = 0; im < 2; ++im) {
#pragma unroll
        for (int in = 0; in < 4; ++in) {
            int ch = wn * 64 + in * 16 + lr;
            float bias = bl[ch];
#pragma unroll
            for (int r = 0; r < 4; ++r) {
                int node = node0 + wm * 32 + im * 16 + lg * 4 + r;
                if (node < N_NODES) {
                    float v = acc[im][in][r] + bias;
                    v = (v > 0.f) ? v : 0.f;
                    out_b[node * C + ch] = f2bf(v);
                }
            }
        }
    }
}

// ---------------------------------------------------------------------------
// Final: logits = h@Wlin + blin (fp32 weights, bf16 h), row log_softmax.
// ---------------------------------------------------------------------------

__global__ __launch_bounds__(256) void k_out(
    const uint* __restrict__ hb, const float* __restrict__ Wlin,
    const float* __restrict__ blin, float* __restrict__ out) {
    __shared__ float sW[C * OUTC];
    __shared__ float sb[OUTC];
    __shared__ __align__(16) float rows[4][C];

    for (int idx = threadIdx.x; idx < C * OUTC; idx += 256) sW[idx] = Wlin[idx];
    if (threadIdx.x < OUTC) sb[threadIdx.x] = blin[threadIdx.x];
    __syncthreads();

    int wv = threadIdx.x >> 6;
    int lane = threadIdx.x & 63;
    for (int node = blockIdx.x * 4 + wv; node < N_NODES; node += gridDim.x * 4) {
        uint v = hb[node * 64 + lane];
        ((float2*)rows[wv])[lane] = make_float2(bflo(v), bfhi(v));
        float acc = sb[lane];
        const float4* r4 = (const float4*)rows[wv];
#pragma unroll
        for (int k4 = 0; k4 < C / 4; ++k4) {
            float4 rv = r4[k4];
            int k = k4 * 4;
            acc += rv.x * sW[(k + 0) * OUTC + lane];
            acc += rv.y * sW[(k + 1) * OUTC + lane];
            acc += rv.z * sW[(k + 2) * OUTC + lane];
            acc += rv.w * sW[(k + 3) * OUTC + lane];
        }
        float m = acc;
#pragma unroll
        for (int o = 32; o > 0; o >>= 1) m = fmaxf(m, __shfl_xor(m, o));
        float ex = __expf(acc - m);
        float ssum = ex;
#pragma unroll
        for (int o = 32; o > 0; o >>= 1) ssum += __shfl_xor(ssum, o);
        out[node * OUTC + lane] = (acc - m) - __logf(ssum);
    }
}

// ---------------------------------------------------------------------------

extern "C" void kernel_launch(void* const* d_in, const int* in_sizes, int n_in,
                              void* d_out, int out_size, void* d_ws,
                              size_t ws_size, hipStream_t stream) {
    const float* x = (const float*)d_in[0];
    const int* ei = (const int*)d_in[1];
    const int* src = ei;
    const int* dst = ei + N_EDGES;
    const float* Wl0 = (const float*)d_in[2];
    const float* bl0 = (const float*)d_in[3];
    const float* Wr0 = (const float*)d_in[4];
    const float* Wl1 = (const float*)d_in[5];
    const float* bl1 = (const float*)d_in[6];
    const float* Wr1 = (const float*)d_in[7];
    const float* Wl2 = (const float*)d_in[8];
    const float* bl2 = (const float*)d_in[9];
    const float* Wr2 = (const float*)d_in[10];
    const float* Wlin = (const float*)d_in[11];
    const float* blin = (const float*)d_in[12];

    // workspace layout (int units; all 16B-aligned)
    int* off = (int*)d_ws;                       // 50004 (N+1 used)
    int* cur = off + 50004;                      // 50000
    int* srcs = cur + 50000;                     // 800000
    float* rinv = (float*)(srcs + 800000);       // 50000
    uint* xb = (uint*)(rinv + 50000);            // N*64
    uint* bufA = xb + (size_t)N_NODES * 64;      // N*64
    uint* bufB = bufA + (size_t)N_NODES * 64;    // N*64
    ushort* w0 = (ushort*)(bufB + (size_t)N_NODES * 64);  // 32768 each
    ushort* w1 = w0 + 32768;
    ushort* w2 = w1 + 32768;

    hipMemsetAsync(off, 0, (size_t)(50004 + 50000) * sizeof(int), stream);

    const int EB = (N_EDGES + 255) / 256;
    k_count<<<EB, 256, 0, stream>>>(dst, off);
    k_scan<<<1, 1024, 0, stream>>>(off, rinv);
    k_fill<<<EB, 256, 0, stream>>>(src, dst, off, cur, srcs);

    k_cast_x<<<(N_NODES * C / 4) / 256, 256, 0, stream>>>((const float4*)x, (uint2*)xb);
    k_prep_w<<<128, 256, 0, stream>>>(Wl0, Wr0, w0);
    k_prep_w<<<128, 256, 0, stream>>>(Wl1, Wr1, w1);
    k_prep_w<<<128, 256, 0, stream>>>(Wl2, Wr2, w2);

    const int AGG_GRID = (N_NODES + 3) / 4;
    const int MM_GRID = (N_NODES + 63) / 64;

    k_aggregate<<<AGG_GRID, 256, 0, stream>>>(xb, off, srcs, rinv, bufA);
    k_mm_mfma<<<MM_GRID, 256, 0, stream>>>((const ushort*)bufA, (const ushort*)xb,
                                           w0, bl0, (ushort*)bufA);

    k_aggregate<<<AGG_GRID, 256, 0, stream>>>(bufA, off, srcs, rinv, bufB);
    k_mm_mfma<<<MM_GRID, 256, 0, stream>>>((const ushort*)bufB, (const ushort*)bufA,
                                           w1, bl1, (ushort*)bufB);

    k_aggregate<<<AGG_GRID, 256, 0, stream>>>(bufB, off, srcs, rinv, bufA);
    k_mm_mfma<<<MM_GRID, 256, 0, stream>>>((const ushort*)bufA, (const ushort*)bufB,
                                           w2, bl2, (ushort*)bufA);

    k_out<<<1024, 256, 0, stream>>>(bufA, Wlin, blin, (float*)d_out);
}

// Round 3
// 305.591 us; speedup vs baseline: 4.1518x; 1.2776x over previous
//
#include <hip/hip_runtime.h>
#include <math.h>

#define N_NODES 50000
#define N_EDGES 800000
#define C 128
#define OUTC 64
#define SCAN_B 98            // ceil(50000 / 512)

typedef __attribute__((ext_vector_type(8))) short bfrag;   // 8 bf16 (4 VGPRs)
typedef __attribute__((ext_vector_type(4))) float ffrag;   // 4 fp32 acc

__device__ __forceinline__ ushort f2bf(float f) {
    uint u = __builtin_bit_cast(uint, f);
    uint r = (u + 0x7FFFu + ((u >> 16) & 1u)) >> 16;       // RNE
    return (ushort)r;
}
__device__ __forceinline__ float bflo(uint v) {            // low bf16 of packed pair
    uint u = v << 16; return __builtin_bit_cast(float, u);
}
__device__ __forceinline__ float bfhi(uint v) {            // high bf16
    uint u = v & 0xFFFF0000u; return __builtin_bit_cast(float, u);
}

// ---------------------------------------------------------------------------
// CSR build
// ---------------------------------------------------------------------------

__global__ void k_count(const int* __restrict__ dst, int* __restrict__ off) {
    int e = blockIdx.x * blockDim.x + threadIdx.x;
    if (e < N_EDGES) atomicAdd(&off[dst[e] + 1], 1);
}

// Two-level scan. k_scan1: block-local inclusive scan of degrees + block sums.
__global__ __launch_bounds__(512) void k_scan1(int* __restrict__ off,
                                               float* __restrict__ rinv,
                                               int* __restrict__ bsum) {
    int i = blockIdx.x * 512 + threadIdx.x;
    int lane = threadIdx.x & 63, wid = threadIdx.x >> 6;
    int deg = (i < N_NODES) ? off[i + 1] : 0;
    int v = deg;
#pragma unroll
    for (int o = 1; o < 64; o <<= 1) {
        int u = __shfl_up(v, o);
        if (lane >= o) v += u;
    }
    __shared__ int ws[8];
    if (lane == 63) ws[wid] = v;
    __syncthreads();
    int base = 0;
#pragma unroll
    for (int w = 0; w < 8; ++w) base += (w < wid) ? ws[w] : 0;
    v += base;
    if (i < N_NODES) {
        off[i + 1] = v;
        rinv[i] = 1.0f / (float)((deg > 1) ? deg : 1);
    }
    if (threadIdx.x == 511) bsum[blockIdx.x] = v;
}

// k_scan2: scan the SCAN_B block totals -> exclusive bases.
__global__ __launch_bounds__(128) void k_scan2(const int* __restrict__ bsum,
                                               int* __restrict__ ebase) {
    int t = threadIdx.x;
    int orig = (t < SCAN_B) ? bsum[t] : 0;
    int v = orig;
#pragma unroll
    for (int o = 1; o < 64; o <<= 1) {
        int u = __shfl_up(v, o);
        if ((t & 63) >= o) v += u;
    }
    __shared__ int w0sum;
    if (t == 63) w0sum = v;
    __syncthreads();
    if (t >= 64) v += w0sum;
    if (t < SCAN_B) ebase[t] = v - orig;
}

// k_scan3: add exclusive base to each block's local scan.
__global__ __launch_bounds__(512) void k_scan3(int* __restrict__ off,
                                               const int* __restrict__ ebase) {
    int i = blockIdx.x * 512 + threadIdx.x;
    if (i < N_NODES) off[i + 1] += ebase[blockIdx.x];
}

__global__ void k_fill(const int* __restrict__ src, const int* __restrict__ dst,
                       const int* __restrict__ off, int* __restrict__ cur,
                       int* __restrict__ srcs) {
    int e = blockIdx.x * blockDim.x + threadIdx.x;
    if (e < N_EDGES) {
        int d = dst[e];
        int pos = off[d] + atomicAdd(&cur[d], 1);
        srcs[pos] = src[e];
    }
}

// ---------------------------------------------------------------------------
// casts / weight packing
// ---------------------------------------------------------------------------

__global__ __launch_bounds__(256) void k_cast_x(const float4* __restrict__ x,
                                                uint2* __restrict__ xb) {
    int i = blockIdx.x * 256 + threadIdx.x;            // over N*C/4 float4s
    float4 v = x[i];
    uint2 o;
    o.x = (uint)f2bf(v.x) | ((uint)f2bf(v.y) << 16);
    o.y = (uint)f2bf(v.z) | ((uint)f2bf(v.w) << 16);
    xb[i] = o;
}

// Pack [Wl;Wr] (K=256, N=128) into fragment-linear bf16:
// dst[((nf*8 + ks)*64 + lane)*8 + j] = Wcat[k][n],
//   n = nf*16 + (lane&15), k = ks*32 + (lane>>4)*8 + j
__global__ __launch_bounds__(256) void k_prep_w(const float* __restrict__ Wl,
                                                const float* __restrict__ Wr,
                                                ushort* __restrict__ dst) {
    int idx = blockIdx.x * 256 + threadIdx.x;          // 0..32767
    int j = idx & 7;
    int lane = (idx >> 3) & 63;
    int ks = (idx >> 9) & 7;
    int nf = idx >> 12;
    int n = nf * 16 + (lane & 15);
    int k = ks * 32 + (lane >> 4) * 8 + j;
    float v = (k < C) ? Wl[k * C + n] : Wr[(k - C) * C + n];
    dst[idx] = f2bf(v);
}

// ---------------------------------------------------------------------------
// Aggregation: wave per node, bf16 rows (lane = 2 channels), 4-deep unroll
// with shfl-broadcast neighbor indices for MLP latency hiding.
// ---------------------------------------------------------------------------

__global__ __launch_bounds__(256) void k_aggregate(
    const uint* __restrict__ hb, const int* __restrict__ off,
    const int* __restrict__ srcs, const float* __restrict__ rinv,
    uint* __restrict__ aggb) {
    int node = blockIdx.x * 4 + (threadIdx.x >> 6);
    if (node >= N_NODES) return;
    int lane = threadIdx.x & 63;
    int b = off[node], e = off[node + 1];
    float sx = 0.f, sy = 0.f;
    for (int j0 = b; j0 < e; j0 += 64) {
        int cnt = e - j0;
        if (cnt > 64) cnt = 64;
        int idx = j0 + lane;
        int sv = srcs[(idx < e) ? idx : (e - 1)];
        int k = 0;
        for (; k + 4 <= cnt; k += 4) {
            int s0 = __shfl(sv, k), s1 = __shfl(sv, k + 1);
            int s2 = __shfl(sv, k + 2), s3 = __shfl(sv, k + 3);
            uint v0 = hb[s0 * 64 + lane], v1 = hb[s1 * 64 + lane];
            uint v2 = hb[s2 * 64 + lane], v3 = hb[s3 * 64 + lane];
            sx += bflo(v0) + bflo(v1) + bflo(v2) + bflo(v3);
            sy += bfhi(v0) + bfhi(v1) + bfhi(v2) + bfhi(v3);
        }
        for (; k < cnt; ++k) {
            int s = __shfl(sv, k);
            uint v = hb[s * 64 + lane];
            sx += bflo(v);
            sy += bfhi(v);
        }
    }
    float r = rinv[node];
    aggb[node * 64 + lane] = (uint)f2bf(sx * r) | ((uint)f2bf(sy * r) << 16);
}

// ---------------------------------------------------------------------------
// MFMA GEMM: out = relu([mean||h] @ Wcat + bl), M-tile 64 nodes, N=128, K=256.
// 4 waves: wave = (wm = node-half, wn = ch-half); per wave 2x4 16x16 frags.
// A staged in LDS with XOR chunk swizzle (G4); B read fragment-linear from
// global (L1/L2-hot). `mean` may alias `out` (per-block row ownership).
// ---------------------------------------------------------------------------

__global__ __launch_bounds__(256) void k_mm_mfma(
    const ushort* mean_b, const ushort* __restrict__ h_b,
    const ushort* __restrict__ Wp, const float* __restrict__ bl,
    ushort* out_b) {
    __shared__ __align__(16) ushort A[64 * 256];   // [row][256 kk], 16B chunks XOR-swizzled

    const int t = threadIdx.x;
    const int node0 = blockIdx.x * 64;

    // --- stage A: thread -> row r = t>>2, chunk-group (t&3)*8 .. +8
    {
        int r = t >> 2;
        int node = node0 + r;
        int cg = (t & 3) * 8;
        for (int i = 0; i < 8; ++i) {
            int c = cg + i;                       // chunk = 8 bf16 = 16B
            uint4 v = make_uint4(0u, 0u, 0u, 0u);
            if (node < N_NODES) {
                int kk = c * 8;
                const ushort* sp = (kk < C) ? &mean_b[node * C + kk]
                                            : &h_b[node * C + (kk - C)];
                v = *(const uint4*)sp;
            }
            int cs = c ^ (r & 7);
            *(uint4*)&A[r * 256 + cs * 8] = v;
        }
    }
    __syncthreads();

    const int w = t >> 6, lane = t & 63;
    const int wm = w >> 1, wn = w & 1;
    const int lg = lane >> 4, lr = lane & 15;

    ffrag acc[2][4];
#pragma unroll
    for (int im = 0; im < 2; ++im)
#pragma unroll
        for (int in = 0; in < 4; ++in) acc[im][in] = (ffrag)0.f;

#pragma unroll 2
    for (int ks = 0; ks < 8; ++ks) {
        bfrag a[2];
#pragma unroll
        for (int im = 0; im < 2; ++im) {
            int r = wm * 32 + im * 16 + lr;
            int c = ks * 4 + lg;                  // chunk index (32 per row)
            int cs = c ^ (r & 7);
            a[im] = *(const bfrag*)&A[r * 256 + cs * 8];
        }
        bfrag b[4];
#pragma unroll
        for (int in = 0; in < 4; ++in) {
            int nf = wn * 4 + in;
            b[in] = *(const bfrag*)&Wp[(((nf * 8) + ks) * 64 + lane) * 8];
        }
#pragma unroll
        for (int im = 0; im < 2; ++im)
#pragma unroll
            for (int in = 0; in < 4; ++in)
                acc[im][in] = __builtin_amdgcn_mfma_f32_16x16x32_bf16(
                    a[im], b[in], acc[im][in], 0, 0, 0);
    }

    // --- epilogue: D row = (lane>>4)*4 + reg, col = lane&15
#pragma unroll
    for (int im = 0; im < 2; ++im) {
#pragma unroll
        for (int in = 0; in < 4; ++in) {
            int ch = wn * 64 + in * 16 + lr;
            float bias = bl[ch];
#pragma unroll
            for (int r = 0; r < 4; ++r) {
                int node = node0 + wm * 32 + im * 16 + lg * 4 + r;
                if (node < N_NODES) {
                    float v = acc[im][in][r] + bias;
                    v = (v > 0.f) ? v : 0.f;
                    out_b[node * C + ch] = f2bf(v);
                }
            }
        }
    }
}

// ---------------------------------------------------------------------------
// Final: logits = h@Wlin + blin (fp32 weights, bf16 h), row log_softmax.
// ---------------------------------------------------------------------------

__global__ __launch_bounds__(256) void k_out(
    const uint* __restrict__ hb, const float* __restrict__ Wlin,
    const float* __restrict__ blin, float* __restrict__ out) {
    __shared__ float sW[C * OUTC];
    __shared__ float sb[OUTC];
    __shared__ __align__(16) float rows[4][C];

    for (int idx = threadIdx.x; idx < C * OUTC; idx += 256) sW[idx] = Wlin[idx];
    if (threadIdx.x < OUTC) sb[threadIdx.x] = blin[threadIdx.x];
    __syncthreads();

    int wv = threadIdx.x >> 6;
    int lane = threadIdx.x & 63;
    for (int node = blockIdx.x * 4 + wv; node < N_NODES; node += gridDim.x * 4) {
        uint v = hb[node * 64 + lane];
        ((float2*)rows[wv])[lane] = make_float2(bflo(v), bfhi(v));
        float acc = sb[lane];
        const float4* r4 = (const float4*)rows[wv];
#pragma unroll
        for (int k4 = 0; k4 < C / 4; ++k4) {
            float4 rv = r4[k4];
            int k = k4 * 4;
            acc += rv.x * sW[(k + 0) * OUTC + lane];
            acc += rv.y * sW[(k + 1) * OUTC + lane];
            acc += rv.z * sW[(k + 2) * OUTC + lane];
            acc += rv.w * sW[(k + 3) * OUTC + lane];
        }
        float m = acc;
#pragma unroll
        for (int o = 32; o > 0; o >>= 1) m = fmaxf(m, __shfl_xor(m, o));
        float ex = __expf(acc - m);
        float ssum = ex;
#pragma unroll
        for (int o = 32; o > 0; o >>= 1) ssum += __shfl_xor(ssum, o);
        out[node * OUTC + lane] = (acc - m) - __logf(ssum);
    }
}

// ---------------------------------------------------------------------------

extern "C" void kernel_launch(void* const* d_in, const int* in_sizes, int n_in,
                              void* d_out, int out_size, void* d_ws,
                              size_t ws_size, hipStream_t stream) {
    const float* x = (const float*)d_in[0];
    const int* ei = (const int*)d_in[1];
    const int* src = ei;
    const int* dst = ei + N_EDGES;
    const float* Wl0 = (const float*)d_in[2];
    const float* bl0 = (const float*)d_in[3];
    const float* Wr0 = (const float*)d_in[4];
    const float* Wl1 = (const float*)d_in[5];
    const float* bl1 = (const float*)d_in[6];
    const float* Wr1 = (const float*)d_in[7];
    const float* Wl2 = (const float*)d_in[8];
    const float* bl2 = (const float*)d_in[9];
    const float* Wr2 = (const float*)d_in[10];
    const float* Wlin = (const float*)d_in[11];
    const float* blin = (const float*)d_in[12];

    // workspace layout (int units; all 16B-aligned)
    int* off = (int*)d_ws;                       // 50004 (N+1 used)
    int* cur = off + 50004;                      // 50000
    int* srcs = cur + 50000;                     // 800000
    float* rinv = (float*)(srcs + 800000);       // 50000
    uint* xb = (uint*)(rinv + 50000);            // N*64
    uint* bufA = xb + (size_t)N_NODES * 64;      // N*64
    uint* bufB = bufA + (size_t)N_NODES * 64;    // N*64
    ushort* w0 = (ushort*)(bufB + (size_t)N_NODES * 64);  // 32768 each
    ushort* w1 = w0 + 32768;
    ushort* w2 = w1 + 32768;
    int* bsum = (int*)(w2 + 32768);              // 128
    int* ebase = bsum + 128;                     // 128

    hipMemsetAsync(off, 0, (size_t)(50004 + 50000) * sizeof(int), stream);

    const int EB = (N_EDGES + 255) / 256;
    k_count<<<EB, 256, 0, stream>>>(dst, off);
    k_scan1<<<SCAN_B, 512, 0, stream>>>(off, rinv, bsum);
    k_scan2<<<1, 128, 0, stream>>>(bsum, ebase);
    k_scan3<<<SCAN_B, 512, 0, stream>>>(off, ebase);
    k_fill<<<EB, 256, 0, stream>>>(src, dst, off, cur, srcs);

    k_cast_x<<<(N_NODES * C / 4) / 256, 256, 0, stream>>>((const float4*)x, (uint2*)xb);
    k_prep_w<<<128, 256, 0, stream>>>(Wl0, Wr0, w0);
    k_prep_w<<<128, 256, 0, stream>>>(Wl1, Wr1, w1);
    k_prep_w<<<128, 256, 0, stream>>>(Wl2, Wr2, w2);

    const int AGG_GRID = (N_NODES + 3) / 4;
    const int MM_GRID = (N_NODES + 63) / 64;

    k_aggregate<<<AGG_GRID, 256, 0, stream>>>(xb, off, srcs, rinv, bufA);
    k_mm_mfma<<<MM_GRID, 256, 0, stream>>>((const ushort*)bufA, (const ushort*)xb,
                                           w0, bl0, (ushort*)bufA);

    k_aggregate<<<AGG_GRID, 256, 0, stream>>>(bufA, off, srcs, rinv, bufB);
    k_mm_mfma<<<MM_GRID, 256, 0, stream>>>((const ushort*)bufB, (const ushort*)bufA,
                                           w1, bl1, (ushort*)bufB);

    k_aggregate<<<AGG_GRID, 256, 0, stream>>>(bufB, off, srcs, rinv, bufA);
    k_mm_mfma<<<MM_GRID, 256, 0, stream>>>((const ushort*)bufA, (const ushort*)bufB,
                                           w2, bl2, (ushort*)bufA);

    k_out<<<1024, 256, 0, stream>>>(bufA, Wlin, blin, (float*)d_out);
}